// Round 6
// baseline (107.009 us; speedup 1.0000x reference)
//
#include <hip/hip_runtime.h>

#define N 8192
#define D 128
// (1/0.07) * log2(e): fold temperature AND base-2 conversion into A-side scale
#define SCALE_A 20.6098592f
#define NBX 64
#define NBY 8
#define NBLK (NBX * NBY)

using short8  = __attribute__((ext_vector_type(8))) short;
using float4v = __attribute__((ext_vector_type(4))) float;

#if __has_builtin(__builtin_amdgcn_exp2f)
#define EXP2(x) __builtin_amdgcn_exp2f(x)
#else
#define EXP2(x) __expf((x) * 0.69314718f)
#endif

// float -> bf16 (RNE) as raw ushort
static __device__ inline unsigned int f2bf(float f) {
    union { float f; unsigned int u; } x;
    x.f = f;
    unsigned int u = x.u;
    return (u + 0x7FFFu + ((u >> 16) & 1u)) >> 16;
}

// Pre-pass: emb fp32 -> bf16 (unscaled, B-side) and bf16*SCALE_A (A-side).
// Also zeroes tot/pos and the ticket. 65536 threads x 16 elements.
__global__ __launch_bounds__(256) void cl_prep(
    const float* __restrict__ emb, unsigned short* __restrict__ bfB,
    unsigned short* __restrict__ bfA, float* __restrict__ tot,
    int* __restrict__ ticket)
{
    const int t = blockIdx.x * 256 + threadIdx.x;
    const float* p = emb + (size_t)t * 16;
    uint4 ob[2], oa[2];
    #pragma unroll
    for (int h = 0; h < 2; ++h) {
        float4v f0 = *(const float4v*)(p + h * 8);
        float4v f1 = *(const float4v*)(p + h * 8 + 4);
        ob[h].x = f2bf(f0[0]) | (f2bf(f0[1]) << 16);
        ob[h].y = f2bf(f0[2]) | (f2bf(f0[3]) << 16);
        ob[h].z = f2bf(f1[0]) | (f2bf(f1[1]) << 16);
        ob[h].w = f2bf(f1[2]) | (f2bf(f1[3]) << 16);
        oa[h].x = f2bf(f0[0] * SCALE_A) | (f2bf(f0[1] * SCALE_A) << 16);
        oa[h].y = f2bf(f0[2] * SCALE_A) | (f2bf(f0[3] * SCALE_A) << 16);
        oa[h].z = f2bf(f1[0] * SCALE_A) | (f2bf(f1[1] * SCALE_A) << 16);
        oa[h].w = f2bf(f1[2] * SCALE_A) | (f2bf(f1[3] * SCALE_A) << 16);
    }
    ((uint4*)bfB)[t * 2]     = ob[0];
    ((uint4*)bfB)[t * 2 + 1] = ob[1];
    ((uint4*)bfA)[t * 2]     = oa[0];
    ((uint4*)bfA)[t * 2 + 1] = oa[1];
    if (t < 2 * N) tot[t] = 0.f;    // tot and pos are contiguous
    if (t == 0) *ticket = 0;
}

// Barrier-free main kernel. Grid (64,8) x 256 threads = 2 blocks/CU.
// Each wave independently computes a 64-row x 512-col strip:
//   wave = (rgrp, chalf): rows = bx*128 + rgrp*64 .. +63;
//   cols = by*1024 + it*128 + chalf*64 .. +63, it = 0..7.
// B fragments load directly from global (bfB = 2 MB, L2-resident on every
// XCD; 4 waves/block hit the same lines -> L1 broadcast). No LDS tile, no
// __syncthreads in the K-loop -> no barrier-drain stalls (R5 lesson: the
// 2-barrier LDS structure was latency-bound at ~40us vs ~13us pipe floor).
// 64-row waves halve B replication vs 32-row (16 KB/wave/tile-iter).
// Register floor ~210 unified -> (256,2); (256,>=3) spills (R2/R3).
// NO agent-scope fences (R4: L2-invalidate thrash, 119us all-idle).
__global__ __launch_bounds__(256, 2) void cl_main(
    const unsigned short* __restrict__ bfA, const unsigned short* __restrict__ bfB,
    const int* __restrict__ labels,
    float* __restrict__ tot, float* __restrict__ pos,
    int* __restrict__ ticket, float* __restrict__ out)
{
    __shared__ float sred[2][4];
    __shared__ int s_ticket;

    const int tid   = threadIdx.x;
    const int lane  = tid & 63;
    const int wave  = tid >> 6;
    const int q     = lane >> 4;   // quad id 0..3
    const int c     = lane & 15;
    const int rgrp  = wave >> 1;   // row group 0..1
    const int chalf = wave & 1;    // col half 0..1
    const int rowbase = blockIdx.x * 128 + rgrp * 64;

    // ---- A fragments: 64 rows, prescaled bf16, loaded once ----
    // A-operand layout (16x16x32): m = lane&15, k = q*8 + j
    short8 afrag[4][4];
    int rowlab[4][4];
    #pragma unroll
    for (int tr = 0; tr < 4; ++tr) {
        const int arow = rowbase + tr * 16 + c;
        #pragma unroll
        for (int ks = 0; ks < 4; ++ks)
            afrag[tr][ks] = *(const short8*)(bfA + (size_t)arow * D + ks * 32 + q * 8);
        // C/D layout rows this lane owns: rowbase + tr*16 + q*4 + reg
        #pragma unroll
        for (int reg = 0; reg < 4; ++reg)
            rowlab[tr][reg] = labels[rowbase + tr * 16 + q * 4 + reg];
    }

    float tot_a[4][4], pos_a[4][4];
    #pragma unroll
    for (int tr = 0; tr < 4; ++tr)
        #pragma unroll
        for (int reg = 0; reg < 4; ++reg) { tot_a[tr][reg] = 0.f; pos_a[tr][reg] = 0.f; }

    for (int it = 0; it < 8; ++it) {
        const int cbase = blockIdx.y * 1024 + it * 128 + chalf * 64;

        int collab[4];
        #pragma unroll
        for (int tc = 0; tc < 4; ++tc) collab[tc] = labels[cbase + tc * 16 + c];

        float4v acc[4][4];
        #pragma unroll
        for (int tr = 0; tr < 4; ++tr)
            #pragma unroll
            for (int tc = 0; tc < 4; ++tc) {
                float4v z = {0.f, 0.f, 0.f, 0.f};
                acc[tr][tc] = z;
            }

        // ---- MFMA: B-frags straight from global (L1/L2-hot) ----
        // B-operand layout == A-operand: n = lane&15, k = q*8 + j
        #pragma unroll
        for (int ks = 0; ks < 4; ++ks) {
            short8 bfr[4];
            #pragma unroll
            for (int tc = 0; tc < 4; ++tc)
                bfr[tc] = *(const short8*)(bfB + (size_t)(cbase + tc * 16 + c) * D
                                           + ks * 32 + q * 8);
            #pragma unroll
            for (int tc = 0; tc < 4; ++tc)
                #pragma unroll
                for (int tr = 0; tr < 4; ++tr)
                    acc[tr][tc] = __builtin_amdgcn_mfma_f32_16x16x32_bf16(
                        afrag[tr][ks], bfr[tc], acc[tr][tc], 0, 0, 0);
        }

        // ---- epilogue: exp2, diagonal/label masking, per-row accumulate ----
        #pragma unroll
        for (int tr = 0; tr < 4; ++tr) {
            const int rtile = rowbase + tr * 16;
            #pragma unroll
            for (int tc = 0; tc < 4; ++tc) {
                const bool diag_tile = (rtile == cbase + tc * 16);  // wave-uniform
                const int lc = collab[tc];
                #pragma unroll
                for (int reg = 0; reg < 4; ++reg) {
                    float v = EXP2(acc[tr][tc][reg]);
                    if (diag_tile && (q * 4 + reg) == c) v = 0.f;  // r == c
                    tot_a[tr][reg] += v;
                    if (rowlab[tr][reg] == lc) pos_a[tr][reg] += v;
                }
            }
        }
    }

    // ---- reduce over the 16 column-lanes, one atomic per row ----
    #pragma unroll
    for (int tr = 0; tr < 4; ++tr)
        #pragma unroll
        for (int reg = 0; reg < 4; ++reg) {
            float t = tot_a[tr][reg];
            float p = pos_a[tr][reg];
            #pragma unroll
            for (int m = 1; m < 16; m <<= 1) {
                t += __shfl_xor(t, m, 64);
                p += __shfl_xor(p, m, 64);
            }
            if (c == 0) {
                const int r = rowbase + tr * 16 + q * 4 + reg;
                atomicAdd(&tot[r], t);   // device-scope RMW at coherent point
                atomicAdd(&pos[r], p);
            }
        }

    // ---- last-block finalize: completion-wait + relaxed ticket (NO cache ops)
    asm volatile("s_waitcnt vmcnt(0)" ::: "memory");  // our atomics committed
    __syncthreads();
    if (tid == 0)
        s_ticket = __hip_atomic_fetch_add(ticket, 1, __ATOMIC_RELAXED,
                                          __HIP_MEMORY_SCOPE_AGENT);
    __syncthreads();
    if (s_ticket != NBLK - 1) return;

    float lsum = 0.f, lcnt = 0.f;
    #pragma unroll 4
    for (int i = tid; i < N; i += 256) {
        const float t = __hip_atomic_load(&tot[i], __ATOMIC_RELAXED,
                                          __HIP_MEMORY_SCOPE_AGENT);
        const float p = __hip_atomic_load(&pos[i], __ATOMIC_RELAXED,
                                          __HIP_MEMORY_SCOPE_AGENT);
        const float loss = -__logf(p / (t + 1e-8f) + 1e-8f);
        if (p > 0.f) { lsum += loss; lcnt += 1.f; }   // valid <=> pos>0
    }
    #pragma unroll
    for (int m = 1; m < 64; m <<= 1) {
        lsum += __shfl_xor(lsum, m, 64);
        lcnt += __shfl_xor(lcnt, m, 64);
    }
    if (lane == 0) { sred[0][wave] = lsum; sred[1][wave] = lcnt; }
    __syncthreads();
    if (tid == 0) {
        const float s = sred[0][0] + sred[0][1] + sred[0][2] + sred[0][3];
        const float n = sred[1][0] + sred[1][1] + sred[1][2] + sred[1][3];
        out[0] = (n > 0.f) ? s / fmaxf(n, 1.f) : 0.f;
    }
}

extern "C" void kernel_launch(void* const* d_in, const int* in_sizes, int n_in,
                              void* d_out, int out_size, void* d_ws, size_t ws_size,
                              hipStream_t stream) {
    const float* emb  = (const float*)d_in[0];
    const int* labels = (const int*)d_in[1];
    unsigned short* bfB = (unsigned short*)d_ws;                       // 2 MB
    unsigned short* bfA = bfB + (size_t)N * D;                         // 2 MB
    float* tot    = (float*)(bfA + (size_t)N * D);
    float* pos    = tot + N;
    int*   ticket = (int*)(pos + N);

    cl_prep<<<256, 256, 0, stream>>>(emb, bfB, bfA, tot, ticket);
    cl_main<<<dim3(NBX, NBY), 256, 0, stream>>>(bfA, bfB, labels, tot, pos,
                                                ticket, (float*)d_out);
}